// Round 6
// baseline (204.037 us; speedup 1.0000x reference)
//
#include <hip/hip_runtime.h>
#include <math.h>

#define EPS 0.3f
#define CAP 64          // fixed per-node edge capacity (Poisson(16): P(deg>64) ~ 1e-18)
#define SPILLCAP 65536  // safety spill list (never used on this input)
#define NR 8            // dst ranges == XCDs
#define NPB 256         // partition blocks

typedef __attribute__((ext_vector_type(8))) short bf16x8;
typedef __attribute__((ext_vector_type(4))) float f32x4;

__device__ __forceinline__ short f2bf(float f) {
    union { float f; unsigned u; } v; v.f = f;
    unsigned r = v.u + 0x7FFFu + ((v.u >> 16) & 1u);  // RNE
    return (short)(r >> 16);
}
__device__ __forceinline__ float bf2f(short s) {
    union { unsigned u; float f; } v;
    v.u = ((unsigned)(unsigned short)s) << 16;
    return v.f;
}
__device__ __forceinline__ int f2bf_pk(float lo, float hi) {
#if __has_builtin(__builtin_amdgcn_cvt_pk_bf16_f32)
    auto r = __builtin_amdgcn_cvt_pk_bf16_f32(lo, hi);
    int out; __builtin_memcpy(&out, &r, 4);
    return out;
#else
    return ((int)(unsigned short)f2bf(lo)) | (((int)(unsigned short)f2bf(hi)) << 16);
#endif
}
// tanh via HW exp: 1 - 2/(1+e^{2x}); saturates correctly, ~1e-6 rel err.
__device__ __forceinline__ float fast_tanh(float x) {
    return 1.0f - 2.0f / (1.0f + __expf(2.0f * x));
}

// K1 (R22): per-block LDS counting-sort of a fixed edge chunk into NR
// dst-range segments (part2[b], offsets hoff[b][0..8]) + all init chores.
// Capacity == chunk size -> lossless, no cursors, no global scan, no spill.
__global__ __launch_bounds__(256) void part_init(
    const int* __restrict__ src, const int* __restrict__ dst, int E,
    const float* __restrict__ w, short* __restrict__ wb,
    int* __restrict__ cnt, int* __restrict__ spillN,
    unsigned* __restrict__ part2, unsigned short* __restrict__ hoff,
    int N, int RSZ, int CS)
{
    extern __shared__ unsigned sbuf[];          // CS entries
    __shared__ int lh[NR], lsc[NR + 1], lcur[NR];
    int b = blockIdx.x, tid = threadIdx.x;
    if (b < 64) wb[b * 256 + tid] = f2bf(w[b * 256 + tid]);
    for (int i = b * 256 + tid; i < N; i += NPB * 256) cnt[i] = 0;
    if (b == 0 && tid == 0) *spillN = 0;

    int e0 = b * CS, e1 = min(e0 + CS, E);
    if (tid < NR) lh[tid] = 0;
    __syncthreads();
    for (int i = e0 + tid; i < e1; i += 256)
        atomicAdd(&lh[(unsigned)dst[i] / (unsigned)RSZ], 1);
    __syncthreads();
    if (tid == 0) {
        int s = 0;
        #pragma unroll
        for (int r = 0; r < NR; ++r) { lsc[r] = s; s += lh[r]; }
        lsc[NR] = s;
    }
    __syncthreads();
    if (tid < NR) lcur[tid] = lsc[tid];
    __syncthreads();
    for (int i = e0 + tid; i < e1; i += 256) {
        int d = dst[i];
        int r = (unsigned)d / (unsigned)RSZ;
        int slot = atomicAdd(&lcur[r], 1);
        sbuf[slot] = ((unsigned)(d - r * RSZ) << 16) | ((unsigned)src[i] & 0xFFFFu);
    }
    __syncthreads();
    int tot = e1 - e0;                          // <=0 for empty tail blocks
    for (int i = tid; i < tot; i += 256)
        part2[(size_t)b * CS + i] = sbuf[i];
    if (tid < NR + 1) hoff[b * (NR + 1) + tid] = (unsigned short)lsc[tid];
}

// K2: blocks [0,SCB): XCD-local scatter from range-sorted segments;
// blocks [SCB,...): t1 MFMA path. Block bid&7==x consumes ONLY range-x
// segments -> cnt atomics + esrc2 dirty lines live in one XCD's L2
// (kills R2's 54MB cross-XCD write amplification without R3's 8x reads).
#define LROW 264   // LDS row stride in shorts (256 + 8 pad): 528 B
__global__ __launch_bounds__(256) void scatter_t1(
    const unsigned* __restrict__ part2, const unsigned short* __restrict__ hoff,
    int* __restrict__ cnt, unsigned short* __restrict__ esrc2,
    unsigned* __restrict__ spill, int* __restrict__ spillN,
    const float* __restrict__ h, const short* __restrict__ wb,
    const float* __restrict__ t1b, const float* __restrict__ gw,
    short* __restrict__ XAh, float* __restrict__ ga0, float* __restrict__ gb0,
    int N, int SCB, int RSZ, int CS)
{
    __shared__ short lds[4][16 * LROW];
    int tid = threadIdx.x;

    if ((int)blockIdx.x < SCB) {
        int x = blockIdx.x & (NR - 1);        // XCD id (heuristic)
        int rank = blockIdx.x >> 3;
        int nb = SCB >> 3;                    // blocks per XCD
        int lo = x * RSZ;
        for (int b = rank; b < NPB; b += nb) {
            int o0 = hoff[b * (NR + 1) + x];
            int o1 = hoff[b * (NR + 1) + x + 1];
            const unsigned* seg = part2 + (size_t)b * CS;
            for (int i = o0 + tid; i < o1; i += 256) {
                unsigned e = __builtin_nontemporal_load(&seg[i]);
                int d = lo + (int)(e >> 16);
                int slot = atomicAdd(&cnt[d], 1);
                if (slot < CAP) {
                    esrc2[(size_t)d * CAP + slot] = (unsigned short)(e & 0xFFFFu);
                } else {
                    int sp = atomicAdd(spillN, 1);
                    if (sp < SPILLCAP)
                        spill[sp] = ((unsigned)d << 16) | (e & 0xFFFFu);
                }
            }
        }
        return;
    }

    // ---- t1 path: x0 = relu(h @ w^T + b) bf16 + fused layer-0 gate dots ----
    int bid = blockIdx.x - SCB;
    int wave = tid >> 6;
    int lane = tid & 63;
    int l15 = lane & 15, quad = lane >> 4;
    int M0 = (bid * 4 + wave) * 16;
    if (M0 >= N) return;                       // wave-uniform condition
    int rlim = N - M0;                         // rows valid in this tile (<=16)

    short* myl = lds[wave];
    const float* hb = h + (size_t)M0 * 256;
    #pragma unroll
    for (int r = 0; r < 16; ++r) {
        if (r < rlim) {
            float4 v = *(const float4*)&hb[(size_t)r * 256 + lane * 4];
            int2 sv; sv.x = f2bf_pk(v.x, v.y); sv.y = f2bf_pk(v.z, v.w);
            *(int2*)&myl[r * LROW + lane * 4] = sv;
        }
    }

    f32x4 acc[4];
    #pragma unroll
    for (int nt = 0; nt < 4; ++nt) acc[nt] = (f32x4){0.f, 0.f, 0.f, 0.f};

    const short* wq = wb + quad * 8;
    #pragma unroll
    for (int kc = 0; kc < 256; kc += 32) {
        bf16x8 af = *(const bf16x8*)&myl[l15 * LROW + kc + quad * 8];
        #pragma unroll
        for (int nt = 0; nt < 4; ++nt) {
            bf16x8 bf = *(const bf16x8*)(wq + (size_t)(nt * 16 + l15) * 256 + kc);
            acc[nt] = __builtin_amdgcn_mfma_f32_16x16x32_bf16(af, bf, acc[nt], 0, 0, 0);
        }
    }

    float pa[4] = {0.f, 0.f, 0.f, 0.f};
    float pb[4] = {0.f, 0.f, 0.f, 0.f};
    #pragma unroll
    for (int nt = 0; nt < 4; ++nt) {
        int n = nt * 16 + l15;
        float bias = t1b[n];
        float gd = gw[n], gs = gw[64 + n];
        #pragma unroll
        for (int r = 0; r < 4; ++r) {
            int row = quad * 4 + r;
            if (row < rlim) {
                float x = fmaxf(acc[nt][r] + bias, 0.f);
                XAh[(size_t)(M0 + row) * 64 + n] = f2bf(x);
                pa[r] += x * gd;
                pb[r] += x * gs;
            }
        }
    }
    #pragma unroll
    for (int off = 1; off < 16; off <<= 1) {
        #pragma unroll
        for (int r = 0; r < 4; ++r) {
            pa[r] += __shfl_xor(pa[r], off, 64);
            pb[r] += __shfl_xor(pb[r], off, 64);
        }
    }
    if (l15 == 0) {
        #pragma unroll
        for (int r = 0; r < 4; ++r) {
            int row = quad * 4 + r;
            if (row < rlim) {
                ga0[M0 + row] = pa[r];
                gb0[M0 + row] = pb[r];
            }
        }
    }
}

// Gather core v5 (unchanged from R5 except nontemporal esrc2 preamble load).
__device__ __forceinline__ void gather_core5(
    const int* __restrict__ cnt, const unsigned short* __restrict__ esrc2,
    const float* __restrict__ a, const float* __restrict__ gb,
    const unsigned* __restrict__ spill, const int* __restrict__ spillN,
    const short* __restrict__ xch, const short* __restrict__ rawh,
    float gbias, int t, int lane, int N, float fin[8])
{
    int g = (lane >> 3) & 3;
    int l = lane & 7;
    int j = lane & 31;
    int hbase = lane & 32;

    int beg = t * CAP;
    int ev_raw = (int)__builtin_nontemporal_load(&esrc2[beg + j]);
    int deg = cnt[t];
    float atg = a[t] + gbias;
    int evc = min(ev_raw, N - 1);

    int degrow = min(deg, CAP);
    int lim = min(degrow, 32);
    int lim1 = max(lim - 1, 0);

    int sarr[8];
    #pragma unroll
    for (int k = 0; k < 8; ++k) {
        int m = g + 4 * k;
        sarr[k] = __shfl(evc, hbase + min(m, lim1), 64);
    }
    bf16x8 xr[8];
    #pragma unroll
    for (int k = 0; k < 8; ++k)
        xr[k] = *(const bf16x8*)&xch[(size_t)sarr[k] * 64 + l * 8];

    float gbe = gb[evc];
    float ce  = (float)cnt[evc];
    float cv = fast_tanh(atg + gbe) * rsqrtf(fmaxf(ce, 1.0f));
    float carr[8];
    #pragma unroll
    for (int k = 0; k < 8; ++k) {
        int m = g + 4 * k;
        float c = __shfl(cv, hbase + min(m, lim1), 64);
        carr[k] = (m < lim) ? c : 0.f;
    }

    float acc[8];
    #pragma unroll
    for (int k = 0; k < 8; ++k) acc[k] = 0.f;
    #pragma unroll
    for (int k = 0; k < 8; ++k) {
        float c0 = carr[k];
        #pragma unroll
        for (int kk = 0; kk < 8; ++kk) acc[kk] += c0 * bf2f(xr[k][kk]);
    }

    for (int i = beg + 32 + g; i < beg + degrow; i += 4) {
        int s0 = (int)esrc2[i];
        float c0 = fast_tanh(atg + gb[s0]) * rsqrtf(fmaxf((float)cnt[s0], 1.f));
        bf16x8 x0 = *(const bf16x8*)&xch[(size_t)s0 * 64 + l * 8];
        #pragma unroll
        for (int k = 0; k < 8; ++k) acc[k] += c0 * bf2f(x0[k]);
    }
    int sn = min(*spillN, SPILLCAP);
    if (sn > 0) {
        for (int i = 0; i < sn; ++i) {
            unsigned e = spill[i];
            if ((int)(e >> 16) == t && g == 0) {
                int s0 = (int)(e & 0xFFFFu);
                float c0 = fast_tanh(atg + gb[s0]) * rsqrtf(fmaxf((float)cnt[s0], 1.f));
                bf16x8 x0 = *(const bf16x8*)&xch[(size_t)s0 * 64 + l * 8];
                #pragma unroll
                for (int k = 0; k < 8; ++k) acc[k] += c0 * bf2f(x0[k]);
            }
        }
    }

    #pragma unroll
    for (int off = 8; off < 32; off <<= 1) {
        #pragma unroll
        for (int k = 0; k < 8; ++k) acc[k] += __shfl_xor(acc[k], off, 64);
    }

    float dt = rsqrtf(fmaxf((float)deg, 1.0f));
    bf16x8 rv = *(const bf16x8*)&rawh[(size_t)t * 64 + l * 8];
    #pragma unroll
    for (int k = 0; k < 8; ++k) fin[k] = EPS * bf2f(rv[k]) + dt * acc[k];
}

// XCD-aligned node map: block bid&7==x handles nodes of range [x*RSZ, ...)
// -> cnt/esrc2 reads hit the L2 the scatter dirtied (same heuristic).
__device__ __forceinline__ void node_map(int bid, int tid, int N, int RSZ,
                                         int& t, int& tt, bool& valid) {
    int x = bid & (NR - 1);
    int q = bid >> 3;
    int ln = q * 8 + (tid >> 5);
    t = x * RSZ + ln;
    int hi = min(x * RSZ + RSZ, N);
    valid = (t < hi);
    tt = valid ? t : max(hi - 1, 0);
}

// layer 0: x1(bf16) = EPS*x0 + gather(x0); next-layer gate dots (ga1, gb1)
__global__ __launch_bounds__(256) void gather_mid(
    const int* __restrict__ cnt, const unsigned short* __restrict__ esrc2,
    const float* __restrict__ a, const float* __restrict__ gb,
    const unsigned* __restrict__ spill, const int* __restrict__ spillN,
    const short* __restrict__ xch, const float* __restrict__ gbp,
    short* __restrict__ xnh, const float* __restrict__ gw_next,
    float* __restrict__ ga_next, float* __restrict__ gb_next, int N, int RSZ)
{
    int tid = threadIdx.x;
    int t, tt; bool valid;
    node_map(blockIdx.x, tid, N, RSZ, t, tt, valid);
    int lane = tid & 63;
    int g = (lane >> 3) & 3, l = lane & 7;
    float fin[8];
    gather_core5(cnt, esrc2, a, gb, spill, spillN, xch, xch, gbp[0], tt, lane, N, fin);

    if (g == 0 && valid) {
        int4 o;
        o.x = f2bf_pk(fin[0], fin[1]); o.y = f2bf_pk(fin[2], fin[3]);
        o.z = f2bf_pk(fin[4], fin[5]); o.w = f2bf_pk(fin[6], fin[7]);
        *(int4*)&xnh[(size_t)tt * 64 + l * 8] = o;
    }
    float av = 0.f, bv = 0.f;
    #pragma unroll
    for (int k = 0; k < 8; ++k) {
        av += fin[k] * gw_next[l * 8 + k];
        bv += fin[k] * gw_next[64 + l * 8 + k];
    }
    #pragma unroll
    for (int off = 1; off < 8; off <<= 1) {
        av += __shfl_xor(av, off, 64);
        bv += __shfl_xor(bv, off, 64);
    }
    if ((lane & 31) == 0 && valid) {
        ga_next[tt] = av;
        gb_next[tt] = bv;
    }
}

// layer 1: fused gather + t2 matmul + log_softmax; x2 never materialized.
__global__ __launch_bounds__(256) void gather_out(
    const int* __restrict__ cnt, const unsigned short* __restrict__ esrc2,
    const float* __restrict__ a, const float* __restrict__ gb,
    const unsigned* __restrict__ spill, const int* __restrict__ spillN,
    const short* __restrict__ xch, const short* __restrict__ rawh,
    const float* __restrict__ gbp, const float* __restrict__ t2w,
    const float* __restrict__ t2b, float* __restrict__ out, int N, int RSZ)
{
    int tid = threadIdx.x;
    int t, tt; bool valid;
    node_map(blockIdx.x, tid, N, RSZ, t, tt, valid);
    int lane = tid & 63;
    int g = (lane >> 3) & 3, l = lane & 7;
    float fin[8];
    gather_core5(cnt, esrc2, a, gb, spill, spillN, xch, rawh, gbp[1], tt, lane, N, fin);

    int j0 = 4 * g;
    float p[4];
    #pragma unroll
    for (int i = 0; i < 4; ++i) {
        const float* w = &t2w[(size_t)(j0 + i) * 64 + l * 8];
        float s = 0.f;
        #pragma unroll
        for (int k = 0; k < 8; ++k) s += fin[k] * w[k];
        p[i] = s;
    }
    #pragma unroll
    for (int off = 1; off < 8; off <<= 1) {
        #pragma unroll
        for (int i = 0; i < 4; ++i) p[i] += __shfl_xor(p[i], off, 64);
    }
    float li[4];
    #pragma unroll
    for (int i = 0; i < 4; ++i) li[i] = p[i] + t2b[j0 + i];
    float m = fmaxf(fmaxf(li[0], li[1]), fmaxf(li[2], li[3]));
    #pragma unroll
    for (int off = 8; off < 32; off <<= 1) m = fmaxf(m, __shfl_xor(m, off, 64));
    float s = 0.f;
    #pragma unroll
    for (int i = 0; i < 4; ++i) s += __expf(li[i] - m);
    #pragma unroll
    for (int off = 8; off < 32; off <<= 1) s += __shfl_xor(s, off, 64);
    float lse = m + __logf(s);
    if (l == 0 && valid) {
        float4 o;
        o.x = li[0] - lse; o.y = li[1] - lse;
        o.z = li[2] - lse; o.w = li[3] - lse;
        *(float4*)&out[(size_t)tt * 16 + j0] = o;
    }
}

extern "C" void kernel_launch(void* const* d_in, const int* in_sizes, int n_in,
                              void* d_out, int out_size, void* d_ws, size_t ws_size,
                              hipStream_t stream) {
    const float* h    = (const float*)d_in[0];
    const int*   src  = (const int*)d_in[1];
    const int*   dst  = (const int*)d_in[2];
    const float* t1w  = (const float*)d_in[3];
    const float* t1b  = (const float*)d_in[4];
    const float* gw   = (const float*)d_in[5];   // [2, 128]
    const float* gbia = (const float*)d_in[6];   // [2]
    const float* t2w  = (const float*)d_in[7];   // [16, 64]
    const float* t2b  = (const float*)d_in[8];   // [16]
    float* out = (float*)d_out;

    int N = in_sizes[0] / 256;                   // 50000 < 65536 (u16 packing)
    int E = in_sizes[1];
    int RSZ = (N + NR - 1) / NR;                 // dst-range size (6250)
    int CS  = (E + NPB - 1) / NPB;               // partition chunk (3125)

    char* p = (char*)d_ws;
    short*    XAh    = (short*)p;       p += (size_t)N * 64 * 2;   // x0 bf16
    short*    XBh    = (short*)p;       p += (size_t)N * 64 * 2;   // x1 bf16
    float*    ga0    = (float*)p;       p += (size_t)N * 4;
    float*    ga1    = (float*)p;       p += (size_t)N * 4;
    float*    gb0    = (float*)p;       p += (size_t)N * 4;
    float*    gb1    = (float*)p;       p += (size_t)N * 4;
    int*      cnt    = (int*)p;         p += (size_t)N * 4;
    int*      spillN = (int*)p;         p += 16;
    unsigned* spill  = (unsigned*)p;    p += (size_t)SPILLCAP * 4;
    p = (char*)(((size_t)p + 15) & ~(size_t)15);
    unsigned short* esrc2 = (unsigned short*)p; p += (size_t)N * CAP * 2;
    p = (char*)(((size_t)p + 15) & ~(size_t)15);
    unsigned* part2  = (unsigned*)p;    p += (size_t)NPB * CS * 4;
    unsigned short* hoff = (unsigned short*)p; p += (size_t)NPB * (NR + 1) * 2;
    p = (char*)(((size_t)p + 15) & ~(size_t)15);
    short*    wbf    = (short*)p;

    // K1: partition (LDS counting sort) + w conversion + cnt zeroing
    part_init<<<NPB, 256, (size_t)CS * 4, stream>>>(
        src, dst, E, t1w, wbf, cnt, spillN, part2, hoff, N, RSZ, CS);

    // K2: XCD-local scatter (blocks 0..SCB-1) || t1+relu MFMA (rest)
    int SCB = 240;
    scatter_t1<<<SCB + (N + 63) / 64, 256, 0, stream>>>(
        part2, hoff, cnt, esrc2, spill, spillN,
        h, wbf, t1b, gw, XAh, ga0, gb0, N, SCB, RSZ, CS);

    int PB = (RSZ + 7) / 8;                      // node blocks per range
    // K3: layer 0 gather — x1(bf16) = EPS*x0 + gather(x0); layer-1 gate dots
    gather_mid<<<NR * PB, 256, 0, stream>>>(cnt, esrc2, ga0, gb0, spill, spillN,
                                            XAh, gbia, XBh, gw + 128, ga1, gb1,
                                            N, RSZ);
    // K4: layer 1 fused gather + t2 + log_softmax
    gather_out<<<NR * PB, 256, 0, stream>>>(cnt, esrc2, ga1, gb1, spill, spillN,
                                            XBh, XAh, gbia, t2w, t2b, out, N, RSZ);
}

// Round 7
// 196.946 us; speedup vs baseline: 1.0360x; 1.0360x over previous
//
#include <hip/hip_runtime.h>
#include <math.h>

#define EPS 0.3f
#define CAP 64          // fixed per-node edge capacity (Poisson(16): P(deg>64) ~ 1e-19)
#define SPILLCAP 65536  // safety spill list (never used on this input)
#define NPB 256         // partition blocks (chunks)

typedef __attribute__((ext_vector_type(8))) short bf16x8;
typedef __attribute__((ext_vector_type(4))) float f32x4;

__device__ __forceinline__ short f2bf(float f) {
    union { float f; unsigned u; } v; v.f = f;
    unsigned r = v.u + 0x7FFFu + ((v.u >> 16) & 1u);  // RNE
    return (short)(r >> 16);
}
__device__ __forceinline__ float bf2f(short s) {
    union { unsigned u; float f; } v;
    v.u = ((unsigned)(unsigned short)s) << 16;
    return v.f;
}
__device__ __forceinline__ int f2bf_pk(float lo, float hi) {
#if __has_builtin(__builtin_amdgcn_cvt_pk_bf16_f32)
    auto r = __builtin_amdgcn_cvt_pk_bf16_f32(lo, hi);
    int out; __builtin_memcpy(&out, &r, 4);
    return out;
#else
    return ((int)(unsigned short)f2bf(lo)) | (((int)(unsigned short)f2bf(hi)) << 16);
#endif
}
// tanh via HW exp: 1 - 2/(1+e^{2x}); saturates correctly, ~1e-6 rel err.
__device__ __forceinline__ float fast_tanh(float x) {
    return 1.0f - 2.0f / (1.0f + __expf(2.0f * x));
}

// K1 (R23): per-chunk LDS counting-sort into 256 FINE bins (dst>>8), offsets
// hoff2[b][0..256] (u16). Same LDS-sort cost as R22's 8-range version, but
// gives the scatter stage bin-exclusive ownership -> no global atomics there.
// Also converts w fp32->bf16 and zeroes spillN. cnt is NOT zeroed (stage 2
// plain-stores it).
__global__ __launch_bounds__(256) void part_init(
    const int* __restrict__ src, const int* __restrict__ dst, int E,
    const float* __restrict__ w, short* __restrict__ wb,
    int* __restrict__ spillN,
    unsigned* __restrict__ part2, unsigned short* __restrict__ hoff2, int CS)
{
    extern __shared__ unsigned sbuf[];          // CS entries
    __shared__ int lh[256], tmp[256], lcur[256];
    int b = blockIdx.x, tid = threadIdx.x;
    if (b < 64) wb[b * 256 + tid] = f2bf(w[b * 256 + tid]);
    if (b == 0 && tid == 0) *spillN = 0;

    int e0 = b * CS, e1 = min(e0 + CS, E);
    lh[tid] = 0;
    __syncthreads();
    for (int i = e0 + tid; i < e1; i += 256)
        atomicAdd(&lh[dst[i] >> 8], 1);
    __syncthreads();
    int v = lh[tid];
    tmp[tid] = v;
    __syncthreads();
    #pragma unroll
    for (int off = 1; off < 256; off <<= 1) {
        int o = (tid >= off) ? tmp[tid - off] : 0;
        __syncthreads();
        tmp[tid] += o;
        __syncthreads();
    }
    int excl = tmp[tid] - v;
    lcur[tid] = excl;
    hoff2[b * 257 + tid] = (unsigned short)excl;
    if (tid == 255) hoff2[b * 257 + 256] = (unsigned short)tmp[255];
    __syncthreads();
    for (int i = e0 + tid; i < e1; i += 256) {
        int d = dst[i];
        int slot = atomicAdd(&lcur[d >> 8], 1);
        sbuf[slot] = ((unsigned)(d & 255) << 16) | ((unsigned)src[i] & 0xFFFFu);
    }
    __syncthreads();
    int tot = e1 - e0;
    for (int i = tid; i < tot; i += 256)
        part2[(size_t)b * CS + i] = sbuf[i];
}

// K2 (R23): blocks [0,NBINS): bin-exclusive bucket fill — block b owns nodes
// [b*256, b*256+256); thread tid streams part-block tid's bin-b sub-segment;
// slot via LDS atomic cursor (no device-scope atomics); esrc2/cnt writes land
// in a block-exclusive 32KB window (single writer -> no cross-XCD line
// sharing, no write amplification). Blocks [NBINS,...): t1 MFMA path.
#define LROW 264   // LDS row stride in shorts (256 + 8 pad): 528 B
__global__ __launch_bounds__(256) void bins_t1(
    const unsigned* __restrict__ part2, const unsigned short* __restrict__ hoff2,
    int* __restrict__ cnt, unsigned short* __restrict__ esrc2,
    unsigned* __restrict__ spill, int* __restrict__ spillN,
    const float* __restrict__ h, const short* __restrict__ wb,
    const float* __restrict__ t1b, const float* __restrict__ gw,
    short* __restrict__ XAh, float* __restrict__ ga0, float* __restrict__ gb0,
    int N, int NBINS, int CS)
{
    __shared__ short lds[4][16 * LROW];
    int tid = threadIdx.x;

    if ((int)blockIdx.x < NBINS) {
        int b = blockIdx.x;
        int t0 = b << 8;
        int* lcur = (int*)&lds[0][0];         // 256 cursors (1KB of the 33KB)
        lcur[tid] = 0;
        __syncthreads();
        // thread tid consumes part-block tid's sub-segment for bin b
        int o0 = hoff2[tid * 257 + b];
        int o1 = hoff2[tid * 257 + b + 1];
        const unsigned* seg = part2 + (size_t)tid * CS;
        for (int i = o0; i < o1; ++i) {
            unsigned e = __builtin_nontemporal_load(&seg[i]);
            int dl = (int)(e >> 16);
            int slot = atomicAdd(&lcur[dl], 1);
            if (slot < CAP) {
                esrc2[(size_t)(t0 + dl) * CAP + slot] = (unsigned short)(e & 0xFFFFu);
            } else {
                int sp = atomicAdd(spillN, 1);
                if (sp < SPILLCAP)
                    spill[sp] = ((unsigned)(t0 + dl) << 16) | (e & 0xFFFFu);
            }
        }
        __syncthreads();
        int t = t0 + tid;
        if (t < N) cnt[t] = lcur[tid];        // plain coalesced store (true deg)
        return;
    }

    // ---- t1 path: x0 = relu(h @ w^T + b) bf16 + fused layer-0 gate dots ----
    int bid = blockIdx.x - NBINS;
    int wave = tid >> 6;
    int lane = tid & 63;
    int l15 = lane & 15, quad = lane >> 4;
    int M0 = (bid * 4 + wave) * 16;
    if (M0 >= N) return;                       // wave-uniform condition
    int rlim = N - M0;                         // rows valid in this tile (<=16)

    short* myl = lds[wave];
    const float* hb = h + (size_t)M0 * 256;
    #pragma unroll
    for (int r = 0; r < 16; ++r) {
        if (r < rlim) {
            float4 v = *(const float4*)&hb[(size_t)r * 256 + lane * 4];
            int2 sv; sv.x = f2bf_pk(v.x, v.y); sv.y = f2bf_pk(v.z, v.w);
            *(int2*)&myl[r * LROW + lane * 4] = sv;
        }
    }

    f32x4 acc[4];
    #pragma unroll
    for (int nt = 0; nt < 4; ++nt) acc[nt] = (f32x4){0.f, 0.f, 0.f, 0.f};

    const short* wq = wb + quad * 8;
    #pragma unroll
    for (int kc = 0; kc < 256; kc += 32) {
        bf16x8 af = *(const bf16x8*)&myl[l15 * LROW + kc + quad * 8];
        #pragma unroll
        for (int nt = 0; nt < 4; ++nt) {
            bf16x8 bf = *(const bf16x8*)(wq + (size_t)(nt * 16 + l15) * 256 + kc);
            acc[nt] = __builtin_amdgcn_mfma_f32_16x16x32_bf16(af, bf, acc[nt], 0, 0, 0);
        }
    }

    float pa[4] = {0.f, 0.f, 0.f, 0.f};
    float pb[4] = {0.f, 0.f, 0.f, 0.f};
    #pragma unroll
    for (int nt = 0; nt < 4; ++nt) {
        int n = nt * 16 + l15;
        float bias = t1b[n];
        float gd = gw[n], gs = gw[64 + n];
        #pragma unroll
        for (int r = 0; r < 4; ++r) {
            int row = quad * 4 + r;
            if (row < rlim) {
                float x = fmaxf(acc[nt][r] + bias, 0.f);
                XAh[(size_t)(M0 + row) * 64 + n] = f2bf(x);
                pa[r] += x * gd;
                pb[r] += x * gs;
            }
        }
    }
    #pragma unroll
    for (int off = 1; off < 16; off <<= 1) {
        #pragma unroll
        for (int r = 0; r < 4; ++r) {
            pa[r] += __shfl_xor(pa[r], off, 64);
            pb[r] += __shfl_xor(pb[r], off, 64);
        }
    }
    if (l15 == 0) {
        #pragma unroll
        for (int r = 0; r < 4; ++r) {
            int row = quad * 4 + r;
            if (row < rlim) {
                ga0[M0 + row] = pa[r];
                gb0[M0 + row] = pb[r];
            }
        }
    }
}

// Gather core v5 (unchanged: branchless, hoisted loads, d_t factored out).
__device__ __forceinline__ void gather_core5(
    const int* __restrict__ cnt, const unsigned short* __restrict__ esrc2,
    const float* __restrict__ a, const float* __restrict__ gb,
    const unsigned* __restrict__ spill, const int* __restrict__ spillN,
    const short* __restrict__ xch, const short* __restrict__ rawh,
    float gbias, int t, int lane, int N, float fin[8])
{
    int g = (lane >> 3) & 3;
    int l = lane & 7;
    int j = lane & 31;
    int hbase = lane & 32;

    int beg = t * CAP;
    int ev_raw = (int)__builtin_nontemporal_load(&esrc2[beg + j]);
    int deg = cnt[t];
    float atg = a[t] + gbias;
    int evc = min(ev_raw, N - 1);

    int degrow = min(deg, CAP);
    int lim = min(degrow, 32);
    int lim1 = max(lim - 1, 0);

    int sarr[8];
    #pragma unroll
    for (int k = 0; k < 8; ++k) {
        int m = g + 4 * k;
        sarr[k] = __shfl(evc, hbase + min(m, lim1), 64);
    }
    bf16x8 xr[8];
    #pragma unroll
    for (int k = 0; k < 8; ++k)
        xr[k] = *(const bf16x8*)&xch[(size_t)sarr[k] * 64 + l * 8];

    float gbe = gb[evc];
    float ce  = (float)cnt[evc];
    float cv = fast_tanh(atg + gbe) * rsqrtf(fmaxf(ce, 1.0f));
    float carr[8];
    #pragma unroll
    for (int k = 0; k < 8; ++k) {
        int m = g + 4 * k;
        float c = __shfl(cv, hbase + min(m, lim1), 64);
        carr[k] = (m < lim) ? c : 0.f;
    }

    float acc[8];
    #pragma unroll
    for (int k = 0; k < 8; ++k) acc[k] = 0.f;
    #pragma unroll
    for (int k = 0; k < 8; ++k) {
        float c0 = carr[k];
        #pragma unroll
        for (int kk = 0; kk < 8; ++kk) acc[kk] += c0 * bf2f(xr[k][kk]);
    }

    for (int i = beg + 32 + g; i < beg + degrow; i += 4) {
        int s0 = (int)esrc2[i];
        float c0 = fast_tanh(atg + gb[s0]) * rsqrtf(fmaxf((float)cnt[s0], 1.f));
        bf16x8 x0 = *(const bf16x8*)&xch[(size_t)s0 * 64 + l * 8];
        #pragma unroll
        for (int k = 0; k < 8; ++k) acc[k] += c0 * bf2f(x0[k]);
    }
    int sn = min(*spillN, SPILLCAP);
    if (sn > 0) {
        for (int i = 0; i < sn; ++i) {
            unsigned e = spill[i];
            if ((int)(e >> 16) == t && g == 0) {
                int s0 = (int)(e & 0xFFFFu);
                float c0 = fast_tanh(atg + gb[s0]) * rsqrtf(fmaxf((float)cnt[s0], 1.f));
                bf16x8 x0 = *(const bf16x8*)&xch[(size_t)s0 * 64 + l * 8];
                #pragma unroll
                for (int k = 0; k < 8; ++k) acc[k] += c0 * bf2f(x0[k]);
            }
        }
    }

    #pragma unroll
    for (int off = 8; off < 32; off <<= 1) {
        #pragma unroll
        for (int k = 0; k < 8; ++k) acc[k] += __shfl_xor(acc[k], off, 64);
    }

    float dt = rsqrtf(fmaxf((float)deg, 1.0f));
    bf16x8 rv = *(const bf16x8*)&rawh[(size_t)t * 64 + l * 8];
    #pragma unroll
    for (int k = 0; k < 8; ++k) fin[k] = EPS * bf2f(rv[k]) + dt * acc[k];
}

// layer 0: x1(bf16) = EPS*x0 + gather(x0); next-layer gate dots (ga1, gb1)
__global__ __launch_bounds__(256) void gather_mid(
    const int* __restrict__ cnt, const unsigned short* __restrict__ esrc2,
    const float* __restrict__ a, const float* __restrict__ gb,
    const unsigned* __restrict__ spill, const int* __restrict__ spillN,
    const short* __restrict__ xch, const float* __restrict__ gbp,
    short* __restrict__ xnh, const float* __restrict__ gw_next,
    float* __restrict__ ga_next, float* __restrict__ gb_next, int N)
{
    int tid = threadIdx.x;
    int t = blockIdx.x * 8 + (tid >> 5);
    int tt = min(t, N - 1);               // clamp: keep all 64 lanes active
    bool valid = (t < N);
    int lane = tid & 63;
    int g = (lane >> 3) & 3, l = lane & 7;
    float fin[8];
    gather_core5(cnt, esrc2, a, gb, spill, spillN, xch, xch, gbp[0], tt, lane, N, fin);

    if (g == 0 && valid) {
        int4 o;
        o.x = f2bf_pk(fin[0], fin[1]); o.y = f2bf_pk(fin[2], fin[3]);
        o.z = f2bf_pk(fin[4], fin[5]); o.w = f2bf_pk(fin[6], fin[7]);
        *(int4*)&xnh[(size_t)tt * 64 + l * 8] = o;
    }
    float av = 0.f, bv = 0.f;
    #pragma unroll
    for (int k = 0; k < 8; ++k) {
        av += fin[k] * gw_next[l * 8 + k];
        bv += fin[k] * gw_next[64 + l * 8 + k];
    }
    #pragma unroll
    for (int off = 1; off < 8; off <<= 1) {
        av += __shfl_xor(av, off, 64);
        bv += __shfl_xor(bv, off, 64);
    }
    if ((lane & 31) == 0 && valid) {
        ga_next[tt] = av;
        gb_next[tt] = bv;
    }
}

// layer 1: fused gather + t2 matmul + log_softmax; x2 never materialized.
__global__ __launch_bounds__(256) void gather_out(
    const int* __restrict__ cnt, const unsigned short* __restrict__ esrc2,
    const float* __restrict__ a, const float* __restrict__ gb,
    const unsigned* __restrict__ spill, const int* __restrict__ spillN,
    const short* __restrict__ xch, const short* __restrict__ rawh,
    const float* __restrict__ gbp, const float* __restrict__ t2w,
    const float* __restrict__ t2b, float* __restrict__ out, int N)
{
    int tid = threadIdx.x;
    int t = blockIdx.x * 8 + (tid >> 5);
    int tt = min(t, N - 1);
    bool valid = (t < N);
    int lane = tid & 63;
    int g = (lane >> 3) & 3, l = lane & 7;
    float fin[8];
    gather_core5(cnt, esrc2, a, gb, spill, spillN, xch, rawh, gbp[1], tt, lane, N, fin);

    int j0 = 4 * g;
    float p[4];
    #pragma unroll
    for (int i = 0; i < 4; ++i) {
        const float* w = &t2w[(size_t)(j0 + i) * 64 + l * 8];
        float s = 0.f;
        #pragma unroll
        for (int k = 0; k < 8; ++k) s += fin[k] * w[k];
        p[i] = s;
    }
    #pragma unroll
    for (int off = 1; off < 8; off <<= 1) {
        #pragma unroll
        for (int i = 0; i < 4; ++i) p[i] += __shfl_xor(p[i], off, 64);
    }
    float li[4];
    #pragma unroll
    for (int i = 0; i < 4; ++i) li[i] = p[i] + t2b[j0 + i];
    float m = fmaxf(fmaxf(li[0], li[1]), fmaxf(li[2], li[3]));
    #pragma unroll
    for (int off = 8; off < 32; off <<= 1) m = fmaxf(m, __shfl_xor(m, off, 64));
    float s = 0.f;
    #pragma unroll
    for (int i = 0; i < 4; ++i) s += __expf(li[i] - m);
    #pragma unroll
    for (int off = 8; off < 32; off <<= 1) s += __shfl_xor(s, off, 64);
    float lse = m + __logf(s);
    if (l == 0 && valid) {
        float4 o;
        o.x = li[0] - lse; o.y = li[1] - lse;
        o.z = li[2] - lse; o.w = li[3] - lse;
        *(float4*)&out[(size_t)tt * 16 + j0] = o;
    }
}

extern "C" void kernel_launch(void* const* d_in, const int* in_sizes, int n_in,
                              void* d_out, int out_size, void* d_ws, size_t ws_size,
                              hipStream_t stream) {
    const float* h    = (const float*)d_in[0];
    const int*   src  = (const int*)d_in[1];
    const int*   dst  = (const int*)d_in[2];
    const float* t1w  = (const float*)d_in[3];
    const float* t1b  = (const float*)d_in[4];
    const float* gw   = (const float*)d_in[5];   // [2, 128]
    const float* gbia = (const float*)d_in[6];   // [2]
    const float* t2w  = (const float*)d_in[7];   // [16, 64]
    const float* t2b  = (const float*)d_in[8];   // [16]
    float* out = (float*)d_out;

    int N = in_sizes[0] / 256;                   // 50000 < 65536 (u16 packing)
    int E = in_sizes[1];
    int CS = (E + NPB - 1) / NPB;                // partition chunk (3125)
    int NBINS = (N + 255) / 256;                 // fine bins (196)

    char* p = (char*)d_ws;
    short*    XAh    = (short*)p;       p += (size_t)N * 64 * 2;   // x0 bf16
    short*    XBh    = (short*)p;       p += (size_t)N * 64 * 2;   // x1 bf16
    float*    ga0    = (float*)p;       p += (size_t)N * 4;
    float*    ga1    = (float*)p;       p += (size_t)N * 4;
    float*    gb0    = (float*)p;       p += (size_t)N * 4;
    float*    gb1    = (float*)p;       p += (size_t)N * 4;
    int*      cnt    = (int*)p;         p += (size_t)N * 4;
    int*      spillN = (int*)p;         p += 16;
    unsigned* spill  = (unsigned*)p;    p += (size_t)SPILLCAP * 4;
    p = (char*)(((size_t)p + 15) & ~(size_t)15);
    unsigned short* esrc2 = (unsigned short*)p; p += (size_t)N * CAP * 2;
    p = (char*)(((size_t)p + 15) & ~(size_t)15);
    unsigned* part2  = (unsigned*)p;    p += (size_t)NPB * CS * 4;
    unsigned short* hoff2 = (unsigned short*)p; p += (size_t)NPB * 257 * 2;
    p = (char*)(((size_t)p + 15) & ~(size_t)15);
    short*    wbf    = (short*)p;

    // K1: fine-bin partition (LDS counting sort) + w conversion
    part_init<<<NPB, 256, (size_t)CS * 4, stream>>>(
        src, dst, E, t1w, wbf, spillN, part2, hoff2, CS);

    // K2: bin-exclusive bucket fill (blocks 0..NBINS-1) || t1 MFMA (rest)
    bins_t1<<<NBINS + (N + 63) / 64, 256, 0, stream>>>(
        part2, hoff2, cnt, esrc2, spill, spillN,
        h, wbf, t1b, gw, XAh, ga0, gb0, N, NBINS, CS);

    int GB = (N + 7) / 8;
    // K3: layer 0 gather — x1(bf16) = EPS*x0 + gather(x0); layer-1 gate dots
    gather_mid<<<GB, 256, 0, stream>>>(cnt, esrc2, ga0, gb0, spill, spillN,
                                       XAh, gbia, XBh, gw + 128, ga1, gb1, N);
    // K4: layer 1 fused gather + t2 + log_softmax
    gather_out<<<GB, 256, 0, stream>>>(cnt, esrc2, ga1, gb1, spill, spillN,
                                       XBh, XAh, gbia, t2w, t2b, out, N);
}

// Round 8
// 191.820 us; speedup vs baseline: 1.0637x; 1.0267x over previous
//
#include <hip/hip_runtime.h>
#include <math.h>

#define EPS 0.3f
#define CAP 64          // fixed per-node edge capacity (Poisson(16): P(deg>64) ~ 1e-19)
#define SPILLCAP 65536  // safety spill list (never used on this input)
#define NPB 256         // partition blocks (chunks)

typedef __attribute__((ext_vector_type(8))) short bf16x8;
typedef __attribute__((ext_vector_type(4))) float f32x4;

__device__ __forceinline__ short f2bf(float f) {
    union { float f; unsigned u; } v; v.f = f;
    unsigned r = v.u + 0x7FFFu + ((v.u >> 16) & 1u);  // RNE
    return (short)(r >> 16);
}
__device__ __forceinline__ float bf2f(short s) {
    union { unsigned u; float f; } v;
    v.u = ((unsigned)(unsigned short)s) << 16;
    return v.f;
}
__device__ __forceinline__ int f2bf_pk(float lo, float hi) {
#if __has_builtin(__builtin_amdgcn_cvt_pk_bf16_f32)
    auto r = __builtin_amdgcn_cvt_pk_bf16_f32(lo, hi);
    int out; __builtin_memcpy(&out, &r, 4);
    return out;
#else
    return ((int)(unsigned short)f2bf(lo)) | (((int)(unsigned short)f2bf(hi)) << 16);
#endif
}
// tanh via HW exp: 1 - 2/(1+e^{2x}); saturates correctly, ~1e-6 rel err.
__device__ __forceinline__ float fast_tanh(float x) {
    return 1.0f - 2.0f / (1.0f + __expf(2.0f * x));
}

// K1 (R23): per-chunk LDS counting-sort into 256 FINE bins (dst>>8), offsets
// hoff2[b][0..256] (u16). Gives the scatter stage bin-exclusive ownership ->
// no global atomics there. Also converts w fp32->bf16 and zeroes spillN.
__global__ __launch_bounds__(256) void part_init(
    const int* __restrict__ src, const int* __restrict__ dst, int E,
    const float* __restrict__ w, short* __restrict__ wb,
    int* __restrict__ spillN,
    unsigned* __restrict__ part2, unsigned short* __restrict__ hoff2, int CS)
{
    extern __shared__ unsigned sbuf[];          // CS entries
    __shared__ int lh[256], tmp[256], lcur[256];
    int b = blockIdx.x, tid = threadIdx.x;
    if (b < 64) wb[b * 256 + tid] = f2bf(w[b * 256 + tid]);
    if (b == 0 && tid == 0) *spillN = 0;

    int e0 = b * CS, e1 = min(e0 + CS, E);
    lh[tid] = 0;
    __syncthreads();
    for (int i = e0 + tid; i < e1; i += 256)
        atomicAdd(&lh[dst[i] >> 8], 1);
    __syncthreads();
    int v = lh[tid];
    tmp[tid] = v;
    __syncthreads();
    #pragma unroll
    for (int off = 1; off < 256; off <<= 1) {
        int o = (tid >= off) ? tmp[tid - off] : 0;
        __syncthreads();
        tmp[tid] += o;
        __syncthreads();
    }
    int excl = tmp[tid] - v;
    lcur[tid] = excl;
    hoff2[b * 257 + tid] = (unsigned short)excl;
    if (tid == 255) hoff2[b * 257 + 256] = (unsigned short)tmp[255];
    __syncthreads();
    for (int i = e0 + tid; i < e1; i += 256) {
        int d = dst[i];
        int slot = atomicAdd(&lcur[d >> 8], 1);
        sbuf[slot] = ((unsigned)(d & 255) << 16) | ((unsigned)src[i] & 0xFFFFu);
    }
    __syncthreads();
    int tot = e1 - e0;
    for (int i = tid; i < tot; i += 256)
        part2[(size_t)b * CS + i] = sbuf[i];
}

// K2 (R24): same as R23 EXCEPT the part2 segment loads are now PLAIN cached
// loads. R7 post-mortem: nontemporal on sequential 4B-per-thread reads
// bypassed L2/L3 -> one full HBM line fetch per 4B element (800K x 64B ~=
// the 51MB FETCH blow-up). Cached, each 64B part2 line serves ~16 loads.
#define LROW 264   // LDS row stride in shorts (256 + 8 pad): 528 B
__global__ __launch_bounds__(256) void bins_t1(
    const unsigned* __restrict__ part2, const unsigned short* __restrict__ hoff2,
    int* __restrict__ cnt, unsigned short* __restrict__ esrc2,
    unsigned* __restrict__ spill, int* __restrict__ spillN,
    const float* __restrict__ h, const short* __restrict__ wb,
    const float* __restrict__ t1b, const float* __restrict__ gw,
    short* __restrict__ XAh, float* __restrict__ ga0, float* __restrict__ gb0,
    int N, int NBINS, int CS)
{
    __shared__ short lds[4][16 * LROW];
    int tid = threadIdx.x;

    if ((int)blockIdx.x < NBINS) {
        int b = blockIdx.x;
        int t0 = b << 8;
        int* lcur = (int*)&lds[0][0];         // 256 cursors (1KB of the 33KB)
        lcur[tid] = 0;
        __syncthreads();
        // thread tid consumes part-block tid's sub-segment for bin b
        int o0 = hoff2[tid * 257 + b];
        int o1 = hoff2[tid * 257 + b + 1];
        const unsigned* seg = part2 + (size_t)tid * CS;
        for (int i = o0; i < o1; ++i) {
            unsigned e = seg[i];              // plain cached load (R24 fix)
            int dl = (int)(e >> 16);
            int slot = atomicAdd(&lcur[dl], 1);
            if (slot < CAP) {
                esrc2[(size_t)(t0 + dl) * CAP + slot] = (unsigned short)(e & 0xFFFFu);
            } else {
                int sp = atomicAdd(spillN, 1);
                if (sp < SPILLCAP)
                    spill[sp] = ((unsigned)(t0 + dl) << 16) | (e & 0xFFFFu);
            }
        }
        __syncthreads();
        int t = t0 + tid;
        if (t < N) cnt[t] = lcur[tid];        // plain coalesced store (true deg)
        return;
    }

    // ---- t1 path: x0 = relu(h @ w^T + b) bf16 + fused layer-0 gate dots ----
    int bid = blockIdx.x - NBINS;
    int wave = tid >> 6;
    int lane = tid & 63;
    int l15 = lane & 15, quad = lane >> 4;
    int M0 = (bid * 4 + wave) * 16;
    if (M0 >= N) return;                       // wave-uniform condition
    int rlim = N - M0;                         // rows valid in this tile (<=16)

    short* myl = lds[wave];
    const float* hb = h + (size_t)M0 * 256;
    #pragma unroll
    for (int r = 0; r < 16; ++r) {
        if (r < rlim) {
            float4 v = *(const float4*)&hb[(size_t)r * 256 + lane * 4];
            int2 sv; sv.x = f2bf_pk(v.x, v.y); sv.y = f2bf_pk(v.z, v.w);
            *(int2*)&myl[r * LROW + lane * 4] = sv;
        }
    }

    f32x4 acc[4];
    #pragma unroll
    for (int nt = 0; nt < 4; ++nt) acc[nt] = (f32x4){0.f, 0.f, 0.f, 0.f};

    const short* wq = wb + quad * 8;
    #pragma unroll
    for (int kc = 0; kc < 256; kc += 32) {
        bf16x8 af = *(const bf16x8*)&myl[l15 * LROW + kc + quad * 8];
        #pragma unroll
        for (int nt = 0; nt < 4; ++nt) {
            bf16x8 bf = *(const bf16x8*)(wq + (size_t)(nt * 16 + l15) * 256 + kc);
            acc[nt] = __builtin_amdgcn_mfma_f32_16x16x32_bf16(af, bf, acc[nt], 0, 0, 0);
        }
    }

    float pa[4] = {0.f, 0.f, 0.f, 0.f};
    float pb[4] = {0.f, 0.f, 0.f, 0.f};
    #pragma unroll
    for (int nt = 0; nt < 4; ++nt) {
        int n = nt * 16 + l15;
        float bias = t1b[n];
        float gd = gw[n], gs = gw[64 + n];
        #pragma unroll
        for (int r = 0; r < 4; ++r) {
            int row = quad * 4 + r;
            if (row < rlim) {
                float x = fmaxf(acc[nt][r] + bias, 0.f);
                XAh[(size_t)(M0 + row) * 64 + n] = f2bf(x);
                pa[r] += x * gd;
                pb[r] += x * gs;
            }
        }
    }
    #pragma unroll
    for (int off = 1; off < 16; off <<= 1) {
        #pragma unroll
        for (int r = 0; r < 4; ++r) {
            pa[r] += __shfl_xor(pa[r], off, 64);
            pb[r] += __shfl_xor(pb[r], off, 64);
        }
    }
    if (l15 == 0) {
        #pragma unroll
        for (int r = 0; r < 4; ++r) {
            int row = quad * 4 + r;
            if (row < rlim) {
                ga0[M0 + row] = pa[r];
                gb0[M0 + row] = pb[r];
            }
        }
    }
}

// Gather core v5 (unchanged: branchless, hoisted loads, d_t factored out).
__device__ __forceinline__ void gather_core5(
    const int* __restrict__ cnt, const unsigned short* __restrict__ esrc2,
    const float* __restrict__ a, const float* __restrict__ gb,
    const unsigned* __restrict__ spill, const int* __restrict__ spillN,
    const short* __restrict__ xch, const short* __restrict__ rawh,
    float gbias, int t, int lane, int N, float fin[8])
{
    int g = (lane >> 3) & 3;
    int l = lane & 7;
    int j = lane & 31;
    int hbase = lane & 32;

    int beg = t * CAP;
    int ev_raw = (int)__builtin_nontemporal_load(&esrc2[beg + j]);
    int deg = cnt[t];
    float atg = a[t] + gbias;
    int evc = min(ev_raw, N - 1);

    int degrow = min(deg, CAP);
    int lim = min(degrow, 32);
    int lim1 = max(lim - 1, 0);

    int sarr[8];
    #pragma unroll
    for (int k = 0; k < 8; ++k) {
        int m = g + 4 * k;
        sarr[k] = __shfl(evc, hbase + min(m, lim1), 64);
    }
    bf16x8 xr[8];
    #pragma unroll
    for (int k = 0; k < 8; ++k)
        xr[k] = *(const bf16x8*)&xch[(size_t)sarr[k] * 64 + l * 8];

    float gbe = gb[evc];
    float ce  = (float)cnt[evc];
    float cv = fast_tanh(atg + gbe) * rsqrtf(fmaxf(ce, 1.0f));
    float carr[8];
    #pragma unroll
    for (int k = 0; k < 8; ++k) {
        int m = g + 4 * k;
        float c = __shfl(cv, hbase + min(m, lim1), 64);
        carr[k] = (m < lim) ? c : 0.f;
    }

    float acc[8];
    #pragma unroll
    for (int k = 0; k < 8; ++k) acc[k] = 0.f;
    #pragma unroll
    for (int k = 0; k < 8; ++k) {
        float c0 = carr[k];
        #pragma unroll
        for (int kk = 0; kk < 8; ++kk) acc[kk] += c0 * bf2f(xr[k][kk]);
    }

    for (int i = beg + 32 + g; i < beg + degrow; i += 4) {
        int s0 = (int)esrc2[i];
        float c0 = fast_tanh(atg + gb[s0]) * rsqrtf(fmaxf((float)cnt[s0], 1.f));
        bf16x8 x0 = *(const bf16x8*)&xch[(size_t)s0 * 64 + l * 8];
        #pragma unroll
        for (int k = 0; k < 8; ++k) acc[k] += c0 * bf2f(x0[k]);
    }
    int sn = min(*spillN, SPILLCAP);
    if (sn > 0) {
        for (int i = 0; i < sn; ++i) {
            unsigned e = spill[i];
            if ((int)(e >> 16) == t && g == 0) {
                int s0 = (int)(e & 0xFFFFu);
                float c0 = fast_tanh(atg + gb[s0]) * rsqrtf(fmaxf((float)cnt[s0], 1.f));
                bf16x8 x0 = *(const bf16x8*)&xch[(size_t)s0 * 64 + l * 8];
                #pragma unroll
                for (int k = 0; k < 8; ++k) acc[k] += c0 * bf2f(x0[k]);
            }
        }
    }

    #pragma unroll
    for (int off = 8; off < 32; off <<= 1) {
        #pragma unroll
        for (int k = 0; k < 8; ++k) acc[k] += __shfl_xor(acc[k], off, 64);
    }

    float dt = rsqrtf(fmaxf((float)deg, 1.0f));
    bf16x8 rv = *(const bf16x8*)&rawh[(size_t)t * 64 + l * 8];
    #pragma unroll
    for (int k = 0; k < 8; ++k) fin[k] = EPS * bf2f(rv[k]) + dt * acc[k];
}

// layer 0: x1(bf16) = EPS*x0 + gather(x0); next-layer gate dots (ga1, gb1)
__global__ __launch_bounds__(256) void gather_mid(
    const int* __restrict__ cnt, const unsigned short* __restrict__ esrc2,
    const float* __restrict__ a, const float* __restrict__ gb,
    const unsigned* __restrict__ spill, const int* __restrict__ spillN,
    const short* __restrict__ xch, const float* __restrict__ gbp,
    short* __restrict__ xnh, const float* __restrict__ gw_next,
    float* __restrict__ ga_next, float* __restrict__ gb_next, int N)
{
    int tid = threadIdx.x;
    int t = blockIdx.x * 8 + (tid >> 5);
    int tt = min(t, N - 1);               // clamp: keep all 64 lanes active
    bool valid = (t < N);
    int lane = tid & 63;
    int g = (lane >> 3) & 3, l = lane & 7;
    float fin[8];
    gather_core5(cnt, esrc2, a, gb, spill, spillN, xch, xch, gbp[0], tt, lane, N, fin);

    if (g == 0 && valid) {
        int4 o;
        o.x = f2bf_pk(fin[0], fin[1]); o.y = f2bf_pk(fin[2], fin[3]);
        o.z = f2bf_pk(fin[4], fin[5]); o.w = f2bf_pk(fin[6], fin[7]);
        *(int4*)&xnh[(size_t)tt * 64 + l * 8] = o;
    }
    float av = 0.f, bv = 0.f;
    #pragma unroll
    for (int k = 0; k < 8; ++k) {
        av += fin[k] * gw_next[l * 8 + k];
        bv += fin[k] * gw_next[64 + l * 8 + k];
    }
    #pragma unroll
    for (int off = 1; off < 8; off <<= 1) {
        av += __shfl_xor(av, off, 64);
        bv += __shfl_xor(bv, off, 64);
    }
    if ((lane & 31) == 0 && valid) {
        ga_next[tt] = av;
        gb_next[tt] = bv;
    }
}

// layer 1: fused gather + t2 matmul + log_softmax; x2 never materialized.
__global__ __launch_bounds__(256) void gather_out(
    const int* __restrict__ cnt, const unsigned short* __restrict__ esrc2,
    const float* __restrict__ a, const float* __restrict__ gb,
    const unsigned* __restrict__ spill, const int* __restrict__ spillN,
    const short* __restrict__ xch, const short* __restrict__ rawh,
    const float* __restrict__ gbp, const float* __restrict__ t2w,
    const float* __restrict__ t2b, float* __restrict__ out, int N)
{
    int tid = threadIdx.x;
    int t = blockIdx.x * 8 + (tid >> 5);
    int tt = min(t, N - 1);
    bool valid = (t < N);
    int lane = tid & 63;
    int g = (lane >> 3) & 3, l = lane & 7;
    float fin[8];
    gather_core5(cnt, esrc2, a, gb, spill, spillN, xch, rawh, gbp[1], tt, lane, N, fin);

    int j0 = 4 * g;
    float p[4];
    #pragma unroll
    for (int i = 0; i < 4; ++i) {
        const float* w = &t2w[(size_t)(j0 + i) * 64 + l * 8];
        float s = 0.f;
        #pragma unroll
        for (int k = 0; k < 8; ++k) s += fin[k] * w[k];
        p[i] = s;
    }
    #pragma unroll
    for (int off = 1; off < 8; off <<= 1) {
        #pragma unroll
        for (int i = 0; i < 4; ++i) p[i] += __shfl_xor(p[i], off, 64);
    }
    float li[4];
    #pragma unroll
    for (int i = 0; i < 4; ++i) li[i] = p[i] + t2b[j0 + i];
    float m = fmaxf(fmaxf(li[0], li[1]), fmaxf(li[2], li[3]));
    #pragma unroll
    for (int off = 8; off < 32; off <<= 1) m = fmaxf(m, __shfl_xor(m, off, 64));
    float s = 0.f;
    #pragma unroll
    for (int i = 0; i < 4; ++i) s += __expf(li[i] - m);
    #pragma unroll
    for (int off = 8; off < 32; off <<= 1) s += __shfl_xor(s, off, 64);
    float lse = m + __logf(s);
    if (l == 0 && valid) {
        float4 o;
        o.x = li[0] - lse; o.y = li[1] - lse;
        o.z = li[2] - lse; o.w = li[3] - lse;
        *(float4*)&out[(size_t)tt * 16 + j0] = o;
    }
}

extern "C" void kernel_launch(void* const* d_in, const int* in_sizes, int n_in,
                              void* d_out, int out_size, void* d_ws, size_t ws_size,
                              hipStream_t stream) {
    const float* h    = (const float*)d_in[0];
    const int*   src  = (const int*)d_in[1];
    const int*   dst  = (const int*)d_in[2];
    const float* t1w  = (const float*)d_in[3];
    const float* t1b  = (const float*)d_in[4];
    const float* gw   = (const float*)d_in[5];   // [2, 128]
    const float* gbia = (const float*)d_in[6];   // [2]
    const float* t2w  = (const float*)d_in[7];   // [16, 64]
    const float* t2b  = (const float*)d_in[8];   // [16]
    float* out = (float*)d_out;

    int N = in_sizes[0] / 256;                   // 50000 < 65536 (u16 packing)
    int E = in_sizes[1];
    int CS = (E + NPB - 1) / NPB;                // partition chunk (3125)
    int NBINS = (N + 255) / 256;                 // fine bins (196)

    char* p = (char*)d_ws;
    short*    XAh    = (short*)p;       p += (size_t)N * 64 * 2;   // x0 bf16
    short*    XBh    = (short*)p;       p += (size_t)N * 64 * 2;   // x1 bf16
    float*    ga0    = (float*)p;       p += (size_t)N * 4;
    float*    ga1    = (float*)p;       p += (size_t)N * 4;
    float*    gb0    = (float*)p;       p += (size_t)N * 4;
    float*    gb1    = (float*)p;       p += (size_t)N * 4;
    int*      cnt    = (int*)p;         p += (size_t)N * 4;
    int*      spillN = (int*)p;         p += 16;
    unsigned* spill  = (unsigned*)p;    p += (size_t)SPILLCAP * 4;
    p = (char*)(((size_t)p + 15) & ~(size_t)15);
    unsigned short* esrc2 = (unsigned short*)p; p += (size_t)N * CAP * 2;
    p = (char*)(((size_t)p + 15) & ~(size_t)15);
    unsigned* part2  = (unsigned*)p;    p += (size_t)NPB * CS * 4;
    unsigned short* hoff2 = (unsigned short*)p; p += (size_t)NPB * 257 * 2;
    p = (char*)(((size_t)p + 15) & ~(size_t)15);
    short*    wbf    = (short*)p;

    // K1: fine-bin partition (LDS counting sort) + w conversion
    part_init<<<NPB, 256, (size_t)CS * 4, stream>>>(
        src, dst, E, t1w, wbf, spillN, part2, hoff2, CS);

    // K2: bin-exclusive bucket fill (blocks 0..NBINS-1) || t1 MFMA (rest)
    bins_t1<<<NBINS + (N + 63) / 64, 256, 0, stream>>>(
        part2, hoff2, cnt, esrc2, spill, spillN,
        h, wbf, t1b, gw, XAh, ga0, gb0, N, NBINS, CS);

    int GB = (N + 7) / 8;
    // K3: layer 0 gather — x1(bf16) = EPS*x0 + gather(x0); layer-1 gate dots
    gather_mid<<<GB, 256, 0, stream>>>(cnt, esrc2, ga0, gb0, spill, spillN,
                                       XAh, gbia, XBh, gw + 128, ga1, gb1, N);
    // K4: layer 1 fused gather + t2 + log_softmax
    gather_out<<<GB, 256, 0, stream>>>(cnt, esrc2, ga1, gb1, spill, spillN,
                                       XBh, XAh, gbia, t2w, t2b, out, N);
}

// Round 9
// 186.473 us; speedup vs baseline: 1.0942x; 1.0287x over previous
//
#include <hip/hip_runtime.h>
#include <math.h>

#define EPS 0.3f
#define CAP 64          // fixed per-node edge capacity (Poisson(16): P(deg>64) ~ 1e-19)
#define SPILLCAP 65536  // safety spill list (never used on this input)
#define NPB 256         // partition blocks (chunks)

typedef __attribute__((ext_vector_type(8))) short bf16x8;
typedef __attribute__((ext_vector_type(4))) float f32x4;

__device__ __forceinline__ short f2bf(float f) {
    union { float f; unsigned u; } v; v.f = f;
    unsigned r = v.u + 0x7FFFu + ((v.u >> 16) & 1u);  // RNE
    return (short)(r >> 16);
}
__device__ __forceinline__ float bf2f(short s) {
    union { unsigned u; float f; } v;
    v.u = ((unsigned)(unsigned short)s) << 16;
    return v.f;
}
__device__ __forceinline__ int f2bf_pk(float lo, float hi) {
#if __has_builtin(__builtin_amdgcn_cvt_pk_bf16_f32)
    auto r = __builtin_amdgcn_cvt_pk_bf16_f32(lo, hi);
    int out; __builtin_memcpy(&out, &r, 4);
    return out;
#else
    return ((int)(unsigned short)f2bf(lo)) | (((int)(unsigned short)f2bf(hi)) << 16);
#endif
}
// tanh via HW exp: 1 - 2/(1+e^{2x}); saturates correctly, ~1e-6 rel err.
__device__ __forceinline__ float fast_tanh(float x) {
    return 1.0f - 2.0f / (1.0f + __expf(2.0f * x));
}

// K1 (R23): per-chunk LDS counting-sort into 256 FINE bins (dst>>8), offsets
// hoff2[b][0..256] (u16). Gives the scatter stage bin-exclusive ownership ->
// no global atomics there. Also converts w fp32->bf16 and zeroes spillN.
__global__ __launch_bounds__(256) void part_init(
    const int* __restrict__ src, const int* __restrict__ dst, int E,
    const float* __restrict__ w, short* __restrict__ wb,
    int* __restrict__ spillN,
    unsigned* __restrict__ part2, unsigned short* __restrict__ hoff2, int CS)
{
    extern __shared__ unsigned sbuf[];          // CS entries
    __shared__ int lh[256], tmp[256], lcur[256];
    int b = blockIdx.x, tid = threadIdx.x;
    if (b < 64) wb[b * 256 + tid] = f2bf(w[b * 256 + tid]);
    if (b == 0 && tid == 0) *spillN = 0;

    int e0 = b * CS, e1 = min(e0 + CS, E);
    lh[tid] = 0;
    __syncthreads();
    for (int i = e0 + tid; i < e1; i += 256)
        atomicAdd(&lh[dst[i] >> 8], 1);
    __syncthreads();
    int v = lh[tid];
    tmp[tid] = v;
    __syncthreads();
    #pragma unroll
    for (int off = 1; off < 256; off <<= 1) {
        int o = (tid >= off) ? tmp[tid - off] : 0;
        __syncthreads();
        tmp[tid] += o;
        __syncthreads();
    }
    int excl = tmp[tid] - v;
    lcur[tid] = excl;
    hoff2[b * 257 + tid] = (unsigned short)excl;
    if (tid == 255) hoff2[b * 257 + 256] = (unsigned short)tmp[255];
    __syncthreads();
    for (int i = e0 + tid; i < e1; i += 256) {
        int d = dst[i];
        int slot = atomicAdd(&lcur[d >> 8], 1);
        sbuf[slot] = ((unsigned)(d & 255) << 16) | ((unsigned)src[i] & 0xFFFFu);
    }
    __syncthreads();
    int tot = e1 - e0;
    for (int i = tid; i < tot; i += 256)
        part2[(size_t)b * CS + i] = sbuf[i];
}

// K2 (R25): bin-exclusive bucket fill + t1 MFMA. The bin path now ALSO
// writes the d = rsqrt(deg) halves of the packed per-node metadata
// md0/md1 = (gb, d) (float2). Disjoint-dword fills: bin path -> .y of both;
// t1 path -> md0.x (gb0); gather_mid -> md1.x (gb1). R8 post-mortem: the
// gathers are random-LINE-REQUEST-bound; packing (gb,cnt->d) 2 requests
// into 1 float2 cuts per-edge random requests 4->3 and removes the
// per-edge rsqrt.
#define LROW 264   // LDS row stride in shorts (256 + 8 pad): 528 B
__global__ __launch_bounds__(256) void bins_t1(
    const unsigned* __restrict__ part2, const unsigned short* __restrict__ hoff2,
    int* __restrict__ cnt, unsigned short* __restrict__ esrc2,
    unsigned* __restrict__ spill, int* __restrict__ spillN,
    const float* __restrict__ h, const short* __restrict__ wb,
    const float* __restrict__ t1b, const float* __restrict__ gw,
    short* __restrict__ XAh, float* __restrict__ ga0,
    float* __restrict__ md0f, float* __restrict__ md1f,
    int N, int NBINS, int CS)
{
    __shared__ short lds[4][16 * LROW];
    int tid = threadIdx.x;

    if ((int)blockIdx.x < NBINS) {
        int b = blockIdx.x;
        int t0 = b << 8;
        int* lcur = (int*)&lds[0][0];         // 256 cursors (1KB of the 33KB)
        lcur[tid] = 0;
        __syncthreads();
        // thread tid consumes part-block tid's sub-segment for bin b
        int o0 = hoff2[tid * 257 + b];
        int o1 = hoff2[tid * 257 + b + 1];
        const unsigned* seg = part2 + (size_t)tid * CS;
        for (int i = o0; i < o1; ++i) {
            unsigned e = seg[i];              // plain cached load (R24 fix)
            int dl = (int)(e >> 16);
            int slot = atomicAdd(&lcur[dl], 1);
            if (slot < CAP) {
                esrc2[(size_t)(t0 + dl) * CAP + slot] = (unsigned short)(e & 0xFFFFu);
            } else {
                int sp = atomicAdd(spillN, 1);
                if (sp < SPILLCAP)
                    spill[sp] = ((unsigned)(t0 + dl) << 16) | (e & 0xFFFFu);
            }
        }
        __syncthreads();
        int t = t0 + tid;
        if (t < N) {
            int dg = lcur[tid];
            cnt[t] = dg;                      // plain coalesced store (true deg)
            float dval = rsqrtf(fmaxf((float)dg, 1.0f));
            md0f[2 * t + 1] = dval;           // .y of md0 (d)
            md1f[2 * t + 1] = dval;           // .y of md1 (d)
        }
        return;
    }

    // ---- t1 path: x0 = relu(h @ w^T + b) bf16 + fused layer-0 gate dots ----
    int bid = blockIdx.x - NBINS;
    int wave = tid >> 6;
    int lane = tid & 63;
    int l15 = lane & 15, quad = lane >> 4;
    int M0 = (bid * 4 + wave) * 16;
    if (M0 >= N) return;                       // wave-uniform condition
    int rlim = N - M0;                         // rows valid in this tile (<=16)

    short* myl = lds[wave];
    const float* hb = h + (size_t)M0 * 256;
    #pragma unroll
    for (int r = 0; r < 16; ++r) {
        if (r < rlim) {
            float4 v = *(const float4*)&hb[(size_t)r * 256 + lane * 4];
            int2 sv; sv.x = f2bf_pk(v.x, v.y); sv.y = f2bf_pk(v.z, v.w);
            *(int2*)&myl[r * LROW + lane * 4] = sv;
        }
    }

    f32x4 acc[4];
    #pragma unroll
    for (int nt = 0; nt < 4; ++nt) acc[nt] = (f32x4){0.f, 0.f, 0.f, 0.f};

    const short* wq = wb + quad * 8;
    #pragma unroll
    for (int kc = 0; kc < 256; kc += 32) {
        bf16x8 af = *(const bf16x8*)&myl[l15 * LROW + kc + quad * 8];
        #pragma unroll
        for (int nt = 0; nt < 4; ++nt) {
            bf16x8 bf = *(const bf16x8*)(wq + (size_t)(nt * 16 + l15) * 256 + kc);
            acc[nt] = __builtin_amdgcn_mfma_f32_16x16x32_bf16(af, bf, acc[nt], 0, 0, 0);
        }
    }

    float pa[4] = {0.f, 0.f, 0.f, 0.f};
    float pb[4] = {0.f, 0.f, 0.f, 0.f};
    #pragma unroll
    for (int nt = 0; nt < 4; ++nt) {
        int n = nt * 16 + l15;
        float bias = t1b[n];
        float gd = gw[n], gs = gw[64 + n];
        #pragma unroll
        for (int r = 0; r < 4; ++r) {
            int row = quad * 4 + r;
            if (row < rlim) {
                float x = fmaxf(acc[nt][r] + bias, 0.f);
                XAh[(size_t)(M0 + row) * 64 + n] = f2bf(x);
                pa[r] += x * gd;
                pb[r] += x * gs;
            }
        }
    }
    #pragma unroll
    for (int off = 1; off < 16; off <<= 1) {
        #pragma unroll
        for (int r = 0; r < 4; ++r) {
            pa[r] += __shfl_xor(pa[r], off, 64);
            pb[r] += __shfl_xor(pb[r], off, 64);
        }
    }
    if (l15 == 0) {
        #pragma unroll
        for (int r = 0; r < 4; ++r) {
            int row = quad * 4 + r;
            if (row < rlim) {
                ga0[M0 + row] = pa[r];
                md0f[2 * (M0 + row)] = pb[r];  // .x of md0 (gb0)
            }
        }
    }
}

// Gather core v6 (R25): per-edge metadata is ONE float2 load (md = gb,d)
// instead of gb + cnt loads + rsqrt. Branchless inner loop, hoisted row
// loads, d_t factored out (applied once post-reduce).
__device__ __forceinline__ void gather_core6(
    const int* __restrict__ cnt, const unsigned short* __restrict__ esrc2,
    const float* __restrict__ a, const float2* __restrict__ md,
    const unsigned* __restrict__ spill, const int* __restrict__ spillN,
    const short* __restrict__ xch, const short* __restrict__ rawh,
    float gbias, int t, int lane, int N, float fin[8])
{
    int g = (lane >> 3) & 3;
    int l = lane & 7;
    int j = lane & 31;
    int hbase = lane & 32;

    int beg = t * CAP;
    // own-node loads (coalesced across the block) + edge row (1 line/node)
    int ev_raw = (int)esrc2[beg + j];
    int deg = cnt[t];
    float2 mdt = md[t];
    float atg = a[t] + gbias;
    int evc = min(ev_raw, N - 1);

    int degrow = min(deg, CAP);
    int lim = min(degrow, 32);
    int lim1 = max(lim - 1, 0);

    int sarr[8];
    #pragma unroll
    for (int k = 0; k < 8; ++k) {
        int m = g + 4 * k;
        sarr[k] = __shfl(evc, hbase + min(m, lim1), 64);
    }
    bf16x8 xr[8];
    #pragma unroll
    for (int k = 0; k < 8; ++k)
        xr[k] = *(const bf16x8*)&xch[(size_t)sarr[k] * 64 + l * 8];

    // coefficient: single random 8B request per edge
    float2 mde = md[evc];
    float cv = fast_tanh(atg + mde.x) * mde.y;   // d_t factored out
    float carr[8];
    #pragma unroll
    for (int k = 0; k < 8; ++k) {
        int m = g + 4 * k;
        float c = __shfl(cv, hbase + min(m, lim1), 64);
        carr[k] = (m < lim) ? c : 0.f;
    }

    float acc[8];
    #pragma unroll
    for (int k = 0; k < 8; ++k) acc[k] = 0.f;
    #pragma unroll
    for (int k = 0; k < 8; ++k) {
        float c0 = carr[k];
        #pragma unroll
        for (int kk = 0; kk < 8; ++kk) acc[kk] += c0 * bf2f(xr[k][kk]);
    }

    // mid tail: slots 32..degrow (Poisson(16): P(deg>32) ~ 1.1e-4)
    for (int i = beg + 32 + g; i < beg + degrow; i += 4) {
        int s0 = (int)esrc2[i];
        float2 m0 = md[s0];
        float c0 = fast_tanh(atg + m0.x) * m0.y;
        bf16x8 x0 = *(const bf16x8*)&xch[(size_t)s0 * 64 + l * 8];
        #pragma unroll
        for (int k = 0; k < 8; ++k) acc[k] += c0 * bf2f(x0[k]);
    }
    // spill list (deg > CAP; essentially never on this input)
    int sn = min(*spillN, SPILLCAP);
    if (sn > 0) {
        for (int i = 0; i < sn; ++i) {
            unsigned e = spill[i];
            if ((int)(e >> 16) == t && g == 0) {
                int s0 = (int)(e & 0xFFFFu);
                float2 m0 = md[s0];
                float c0 = fast_tanh(atg + m0.x) * m0.y;
                bf16x8 x0 = *(const bf16x8*)&xch[(size_t)s0 * 64 + l * 8];
                #pragma unroll
                for (int k = 0; k < 8; ++k) acc[k] += c0 * bf2f(x0[k]);
            }
        }
    }

    // reduce across the 4 edge groups (lane bits 3,4; stays within half-wave)
    #pragma unroll
    for (int off = 8; off < 32; off <<= 1) {
        #pragma unroll
        for (int k = 0; k < 8; ++k) acc[k] += __shfl_xor(acc[k], off, 64);
    }

    // epilogue: apply d_t once (precomputed in md); add residual
    bf16x8 rv = *(const bf16x8*)&rawh[(size_t)t * 64 + l * 8];
    #pragma unroll
    for (int k = 0; k < 8; ++k) fin[k] = EPS * bf2f(rv[k]) + mdt.y * acc[k];
}

// layer 0: x1(bf16) = EPS*x0 + gather(x0); next-layer gate dots (ga1, md1.x)
__global__ __launch_bounds__(256) void gather_mid(
    const int* __restrict__ cnt, const unsigned short* __restrict__ esrc2,
    const float* __restrict__ a, const float2* __restrict__ md,
    const unsigned* __restrict__ spill, const int* __restrict__ spillN,
    const short* __restrict__ xch, const float* __restrict__ gbp,
    short* __restrict__ xnh, const float* __restrict__ gw_next,
    float* __restrict__ ga_next, float* __restrict__ md_next_f, int N)
{
    int tid = threadIdx.x;
    int t = blockIdx.x * 8 + (tid >> 5);
    int tt = min(t, N - 1);               // clamp: keep all 64 lanes active
    bool valid = (t < N);
    int lane = tid & 63;
    int g = (lane >> 3) & 3, l = lane & 7;
    float fin[8];
    gather_core6(cnt, esrc2, a, md, spill, spillN, xch, xch, gbp[0], tt, lane, N, fin);

    if (g == 0 && valid) {
        int4 o;
        o.x = f2bf_pk(fin[0], fin[1]); o.y = f2bf_pk(fin[2], fin[3]);
        o.z = f2bf_pk(fin[4], fin[5]); o.w = f2bf_pk(fin[6], fin[7]);
        *(int4*)&xnh[(size_t)tt * 64 + l * 8] = o;
    }
    float av = 0.f, bv = 0.f;
    #pragma unroll
    for (int k = 0; k < 8; ++k) {
        av += fin[k] * gw_next[l * 8 + k];
        bv += fin[k] * gw_next[64 + l * 8 + k];
    }
    #pragma unroll
    for (int off = 1; off < 8; off <<= 1) {
        av += __shfl_xor(av, off, 64);
        bv += __shfl_xor(bv, off, 64);
    }
    if ((lane & 31) == 0 && valid) {
        ga_next[tt] = av;
        md_next_f[2 * tt] = bv;           // .x of md1 (gb1); .y prefilled
    }
}

// layer 1: fused gather + t2 matmul + log_softmax; x2 never materialized.
__global__ __launch_bounds__(256) void gather_out(
    const int* __restrict__ cnt, const unsigned short* __restrict__ esrc2,
    const float* __restrict__ a, const float2* __restrict__ md,
    const unsigned* __restrict__ spill, const int* __restrict__ spillN,
    const short* __restrict__ xch, const short* __restrict__ rawh,
    const float* __restrict__ gbp, const float* __restrict__ t2w,
    const float* __restrict__ t2b, float* __restrict__ out, int N)
{
    int tid = threadIdx.x;
    int t = blockIdx.x * 8 + (tid >> 5);
    int tt = min(t, N - 1);
    bool valid = (t < N);
    int lane = tid & 63;
    int g = (lane >> 3) & 3, l = lane & 7;
    float fin[8];
    gather_core6(cnt, esrc2, a, md, spill, spillN, xch, rawh, gbp[1], tt, lane, N, fin);

    int j0 = 4 * g;
    float p[4];
    #pragma unroll
    for (int i = 0; i < 4; ++i) {
        const float* w = &t2w[(size_t)(j0 + i) * 64 + l * 8];
        float s = 0.f;
        #pragma unroll
        for (int k = 0; k < 8; ++k) s += fin[k] * w[k];
        p[i] = s;
    }
    #pragma unroll
    for (int off = 1; off < 8; off <<= 1) {
        #pragma unroll
        for (int i = 0; i < 4; ++i) p[i] += __shfl_xor(p[i], off, 64);
    }
    float li[4];
    #pragma unroll
    for (int i = 0; i < 4; ++i) li[i] = p[i] + t2b[j0 + i];
    float m = fmaxf(fmaxf(li[0], li[1]), fmaxf(li[2], li[3]));
    #pragma unroll
    for (int off = 8; off < 32; off <<= 1) m = fmaxf(m, __shfl_xor(m, off, 64));
    float s = 0.f;
    #pragma unroll
    for (int i = 0; i < 4; ++i) s += __expf(li[i] - m);
    #pragma unroll
    for (int off = 8; off < 32; off <<= 1) s += __shfl_xor(s, off, 64);
    float lse = m + __logf(s);
    if (l == 0 && valid) {
        float4 o;
        o.x = li[0] - lse; o.y = li[1] - lse;
        o.z = li[2] - lse; o.w = li[3] - lse;
        *(float4*)&out[(size_t)tt * 16 + j0] = o;
    }
}

extern "C" void kernel_launch(void* const* d_in, const int* in_sizes, int n_in,
                              void* d_out, int out_size, void* d_ws, size_t ws_size,
                              hipStream_t stream) {
    const float* h    = (const float*)d_in[0];
    const int*   src  = (const int*)d_in[1];
    const int*   dst  = (const int*)d_in[2];
    const float* t1w  = (const float*)d_in[3];
    const float* t1b  = (const float*)d_in[4];
    const float* gw   = (const float*)d_in[5];   // [2, 128]
    const float* gbia = (const float*)d_in[6];   // [2]
    const float* t2w  = (const float*)d_in[7];   // [16, 64]
    const float* t2b  = (const float*)d_in[8];   // [16]
    float* out = (float*)d_out;

    int N = in_sizes[0] / 256;                   // 50000 < 65536 (u16 packing)
    int E = in_sizes[1];
    int CS = (E + NPB - 1) / NPB;                // partition chunk (3125)
    int NBINS = (N + 255) / 256;                 // fine bins (196)

    char* p = (char*)d_ws;
    short*    XAh    = (short*)p;       p += (size_t)N * 64 * 2;   // x0 bf16
    short*    XBh    = (short*)p;       p += (size_t)N * 64 * 2;   // x1 bf16
    float*    ga0    = (float*)p;       p += (size_t)N * 4;
    float*    ga1    = (float*)p;       p += (size_t)N * 4;
    float2*   md0    = (float2*)p;      p += (size_t)N * 8;        // (gb0, d)
    float2*   md1    = (float2*)p;      p += (size_t)N * 8;        // (gb1, d)
    int*      cnt    = (int*)p;         p += (size_t)N * 4;
    int*      spillN = (int*)p;         p += 16;
    unsigned* spill  = (unsigned*)p;    p += (size_t)SPILLCAP * 4;
    p = (char*)(((size_t)p + 15) & ~(size_t)15);
    unsigned short* esrc2 = (unsigned short*)p; p += (size_t)N * CAP * 2;
    p = (char*)(((size_t)p + 15) & ~(size_t)15);
    unsigned* part2  = (unsigned*)p;    p += (size_t)NPB * CS * 4;
    unsigned short* hoff2 = (unsigned short*)p; p += (size_t)NPB * 257 * 2;
    p = (char*)(((size_t)p + 15) & ~(size_t)15);
    short*    wbf    = (short*)p;

    // K1: fine-bin partition (LDS counting sort) + w conversion
    part_init<<<NPB, 256, (size_t)CS * 4, stream>>>(
        src, dst, E, t1w, wbf, spillN, part2, hoff2, CS);

    // K2: bin-exclusive bucket fill + md.y (blocks 0..NBINS-1) || t1 MFMA
    bins_t1<<<NBINS + (N + 63) / 64, 256, 0, stream>>>(
        part2, hoff2, cnt, esrc2, spill, spillN,
        h, wbf, t1b, gw, XAh, ga0, (float*)md0, (float*)md1, N, NBINS, CS);

    int GB = (N + 7) / 8;
    // K3: layer 0 gather — x1(bf16) = EPS*x0 + gather(x0); layer-1 gate dots
    gather_mid<<<GB, 256, 0, stream>>>(cnt, esrc2, ga0, md0, spill, spillN,
                                       XAh, gbia, XBh, gw + 128, ga1,
                                       (float*)md1, N);
    // K4: layer 1 fused gather + t2 + log_softmax
    gather_out<<<GB, 256, 0, stream>>>(cnt, esrc2, ga1, md1, spill, spillN,
                                       XBh, XAh, gbia, t2w, t2b, out, N);
}